// Round 6
// baseline (626.074 us; speedup 1.0000x reference)
//
#include <hip/hip_runtime.h>
#include <stdint.h>

#define T_STEPS 512
#define BATCH   32
#define DIMN    1024
#define MROWS   (T_STEPS*BATCH)   // 16384
#define BD      (BATCH*DIMN)      // 32768

typedef _Float16 f16;
typedef _Float16 f16x8 __attribute__((ext_vector_type(8)));
typedef _Float16 f16x2 __attribute__((ext_vector_type(2)));
typedef float    f32x4 __attribute__((ext_vector_type(4)));

union U8 { f16x8 v; f16x2 p[4]; };

// packed f32x2 -> f16x2 (RTZ)
__device__ __forceinline__ f16x2 pkrtz(float a, float b) {
  return __builtin_bit_cast(f16x2, __builtin_amdgcn_cvt_pkrtz(a, b));
}

// ---------- async global -> LDS, 16 B per lane ----------
__device__ __forceinline__ void load16_to_lds(const f16* gptr, f16* lptr) {
  __builtin_amdgcn_global_load_lds(
      (const __attribute__((address_space(1))) unsigned int*)(uintptr_t)gptr,
      (__attribute__((address_space(3))) unsigned int*)(uint32_t)(uintptr_t)lptr,
      16, 0, 0);
}

// ---------- DPP row-rotate add ----------
template<int CTRL>
__device__ __forceinline__ float dpp_ror_add(float v) {
  int iv = __float_as_int(v);
  int rv = __builtin_amdgcn_update_dpp(iv, iv, CTRL, 0xF, 0xF, false);
  return v + __int_as_float(rv);
}

// all-lanes sum of 64 lanes
__device__ __forceinline__ float wave_allsum(float s) {
  s = dpp_ror_add<0x128>(s);   // row_ror:8
  s = dpp_ror_add<0x124>(s);   // row_ror:4
  s = dpp_ror_add<0x122>(s);   // row_ror:2
  s = dpp_ror_add<0x121>(s);   // row_ror:1
  float a = __int_as_float(__builtin_amdgcn_readlane(__float_as_int(s), 0));
  float b = __int_as_float(__builtin_amdgcn_readlane(__float_as_int(s), 16));
  float c = __int_as_float(__builtin_amdgcn_readlane(__float_as_int(s), 32));
  float d = __int_as_float(__builtin_amdgcn_readlane(__float_as_int(s), 48));
  return (a + b) + (c + d);
}

// ---------- f32 -> f16 convert, 8 elems/thread ----------
__global__ __launch_bounds__(256) void cvt_f32_f16(const float* __restrict__ src,
                                                   f16* __restrict__ dst, int n8) {
  int i = blockIdx.x * 256 + threadIdx.x;
  if (i >= n8) return;
  const float4* s = (const float4*)src;
  float4 a = s[2*i], b = s[2*i + 1];
  f16x8 o = { (f16)a.x, (f16)a.y, (f16)a.z, (f16)a.w,
              (f16)b.x, (f16)b.y, (f16)b.z, (f16)b.w };
  *(f16x8*)(dst + (size_t)i * 8) = o;
}

// ---------- 128x128-tile fp16 MFMA GEMM (unchanged, verified) ----------
// mode 0: Cout = (f16)( exp(la)      * (acc + bias[n]) )
// mode 1: Cout = (f16)( addend[m,n] + 0.1*sigmoid(lb)*rowscale_bmajor[m]*acc )
//   rowscale layout (mode 1): S[b][t], stride 512  (row m = t*BATCH + b)
__global__ __launch_bounds__(256) void gemm_bt_f16(
    const f16* __restrict__ A, const f16* __restrict__ B,
    const float* __restrict__ bias, f16* __restrict__ Cout,
    const float* __restrict__ la, const float* __restrict__ lb,
    const float* __restrict__ rowscale, const f16* __restrict__ addend, int mode) {
  constexpr int K = DIMN;
  constexpr int N = DIMN;
  __shared__ f16 Alds[128 * 32];
  __shared__ f16 Blds[128 * 32];
  const int tid  = threadIdx.x;
  const int lane = tid & 63;
  const int wid  = tid >> 6;
  const int wm = wid & 1, wn = wid >> 1;
  const int l15  = lane & 15;
  const int quad = lane >> 4;
  const int swz  = (l15 >> 1) & 3;
  const int rowBase = blockIdx.x * 128;
  const int colBase = blockIdx.y * 128;
  const int sr = lane >> 2;
  const int cs = lane & 3;

  const float scale = (mode == 0) ? expf(la[0])
                                  : 0.1f / (1.0f + expf(-lb[0]));

  f32x4 acc[4][4] = {};

  for (int k0 = 0; k0 < K; k0 += 32) {
    #pragma unroll
    for (int i = 0; i < 2; ++i) {
      const int g = wid + i * 4;
      const int r = g * 16 + sr;
      const int cd = cs ^ ((r >> 1) & 3);
      load16_to_lds(A + (size_t)(rowBase + r) * K + k0 + cd * 8, Alds + g * 512);
      load16_to_lds(B + (size_t)(colBase + r) * K + k0 + cd * 8, Blds + g * 512);
    }
    __syncthreads();
    f16x8 af[4], bf[4];
    #pragma unroll
    for (int mi = 0; mi < 4; ++mi) {
      const int r = wm * 64 + mi * 16 + l15;
      af[mi] = *(const f16x8*)(Alds + r * 32 + (quad ^ swz) * 8);
    }
    #pragma unroll
    for (int ni = 0; ni < 4; ++ni) {
      const int r = wn * 64 + ni * 16 + l15;
      bf[ni] = *(const f16x8*)(Blds + r * 32 + (quad ^ swz) * 8);
    }
    #pragma unroll
    for (int mi = 0; mi < 4; ++mi)
      #pragma unroll
      for (int ni = 0; ni < 4; ++ni)
        acc[mi][ni] = __builtin_amdgcn_mfma_f32_16x16x32_f16(af[mi], bf[ni], acc[mi][ni], 0, 0, 0);
    __syncthreads();
  }

  float colb[4];
  #pragma unroll
  for (int ni = 0; ni < 4; ++ni)
    colb[ni] = (mode == 0) ? bias[colBase + wn * 64 + ni * 16 + l15] : 0.0f;

  #pragma unroll
  for (int mi = 0; mi < 4; ++mi) {
    const int m0 = rowBase + wm * 64 + mi * 16 + quad * 4;
    #pragma unroll
    for (int j = 0; j < 4; ++j) {
      const size_t row = (size_t)(m0 + j);
      const float rs = (mode == 0)
          ? scale
          : scale * rowscale[(((int)row & 31) << 9) | ((int)row >> 5)];
      #pragma unroll
      for (int ni = 0; ni < 4; ++ni) {
        const int n = colBase + wn * 64 + ni * 16 + l15;
        float v;
        if (mode == 0) v = rs * (acc[mi][ni][j] + colb[ni]);
        else           v = fmaf(rs, acc[mi][ni][j], (float)addend[row * N + n]);
        Cout[row * N + n] = (f16)v;
      }
    }
  }
}

// ---------- batched Gram: Gout[b][t][s] = w_t . w_s  (upper-triangle tiles only) ----------
// A is [T,B,D] t-major: row s of batch b at A + s*BD + b*DIMN (row stride BD).
__global__ __launch_bounds__(256) void gram_f16(
    const f16* __restrict__ A, f16* __restrict__ Gout) {
  const int bx = blockIdx.x, by = blockIdx.y, bz = blockIdx.z;
  if (by < bx) return;                       // d-update only reads cols s >= row t
  __shared__ f16 Alds[128 * 32];
  __shared__ f16 Blds[128 * 32];
  const int tid  = threadIdx.x;
  const int lane = tid & 63;
  const int wid  = tid >> 6;
  const int wm = wid & 1, wn = wid >> 1;
  const int l15  = lane & 15;
  const int quad = lane >> 4;
  const int swz  = (l15 >> 1) & 3;
  const int rowBase = bx * 128;
  const int colBase = by * 128;
  const int sr = lane >> 2;
  const int cs = lane & 3;
  const f16* Ab = A + (size_t)bz * DIMN;

  f32x4 acc[4][4] = {};

  for (int k0 = 0; k0 < DIMN; k0 += 32) {
    #pragma unroll
    for (int i = 0; i < 2; ++i) {
      const int g = wid + i * 4;
      const int r = g * 16 + sr;
      const int cd = cs ^ ((r >> 1) & 3);
      load16_to_lds(Ab + (size_t)(rowBase + r) * BD + k0 + cd * 8, Alds + g * 512);
      load16_to_lds(Ab + (size_t)(colBase + r) * BD + k0 + cd * 8, Blds + g * 512);
    }
    __syncthreads();
    f16x8 af[4], bf[4];
    #pragma unroll
    for (int mi = 0; mi < 4; ++mi) {
      const int r = wm * 64 + mi * 16 + l15;
      af[mi] = *(const f16x8*)(Alds + r * 32 + (quad ^ swz) * 8);
    }
    #pragma unroll
    for (int ni = 0; ni < 4; ++ni) {
      const int r = wn * 64 + ni * 16 + l15;
      bf[ni] = *(const f16x8*)(Blds + r * 32 + (quad ^ swz) * 8);
    }
    #pragma unroll
    for (int mi = 0; mi < 4; ++mi)
      #pragma unroll
      for (int ni = 0; ni < 4; ++ni)
        acc[mi][ni] = __builtin_amdgcn_mfma_f32_16x16x32_f16(af[mi], bf[ni], acc[mi][ni], 0, 0, 0);
    __syncthreads();
  }

  f16* Gb = Gout + (size_t)bz * (T_STEPS * T_STEPS);
  #pragma unroll
  for (int mi = 0; mi < 4; ++mi) {
    const int m0 = rowBase + wm * 64 + mi * 16 + quad * 4;
    #pragma unroll
    for (int j = 0; j < 4; ++j) {
      #pragma unroll
      for (int ni = 0; ni < 4; ++ni) {
        const int n = colBase + wn * 64 + ni * 16 + l15;
        Gb[(size_t)(m0 + j) * T_STEPS + n] = (f16)acc[mi][ni][j];
      }
    }
  }
}

// ---------- P[b][s] = h0[b] . w_s ----------
__global__ __launch_bounds__(256) void gemv_p(
    const f16* __restrict__ Wm, const float* __restrict__ h0,
    float* __restrict__ P) {
  const int b = blockIdx.x, sg = blockIdx.y;
  const int w = threadIdx.x >> 6, l = threadIdx.x & 63;
  float h[16];
  {
    const float* hp = h0 + (size_t)b * DIMN + l * 16;
    #pragma unroll
    for (int i = 0; i < 4; ++i) {
      float4 a = *(const float4*)(hp + i * 4);
      h[i*4+0] = a.x; h[i*4+1] = a.y; h[i*4+2] = a.z; h[i*4+3] = a.w;
    }
  }
  for (int k = 0; k < 16; ++k) {
    const int s = sg * 64 + w * 16 + k;
    const f16* wp = Wm + (size_t)s * BD + (size_t)b * DIMN + l * 16;
    f16x8 a0 = *(const f16x8*)(wp);
    f16x8 a1 = *(const f16x8*)(wp + 8);
    float acc = 0.f;
    #pragma unroll
    for (int i = 0; i < 8; ++i) acc = fmaf((float)a0[i], h[i], acc);
    #pragma unroll
    for (int i = 0; i < 8; ++i) acc = fmaf((float)a1[i], h[i+8], acc);
    acc = wave_allsum(acc);
    if (l == 0) P[(size_t)b * 512 + s] = acc;
  }
}

// ---------- scalar scan: the sequential chain, D-free ----------
// Per batch (1 wave): slot s=8l+j lives in lane l reg j.
//   d[s] = u_t . w_s   (init P[s]; update d[s] += c_t * g[t][s])
//   N    = ||u_t||^2   (init ||h0||^2; N += 2 c_t d[t] + c_t^2 g_tt)
//   m = N*kk + eps; rho = rsqrt(m); c *= m*rho; ic *= rho; kk *= rho^2
// Outputs: Carr[b][t] = c_t; Sarr: SHIFT=1 -> S[b][t+1]=ic_{t+1}, S[b][0]=1;
//          SHIFT=0 -> S[b][t]=ic_{t+1}.
template<int SHIFT>
__global__ __launch_bounds__(64, 1) void scalar_scan(
    const f16* __restrict__ Gm, const float* __restrict__ P,
    const float* __restrict__ h0,
    float* __restrict__ Carr, float* __restrict__ Sarr) {
  const int b = blockIdx.x, l = threadIdx.x;
  const f16* Gb = Gm + (size_t)b * (T_STEPS * T_STEPS);
  float N;
  {
    const float* hp = h0 + (size_t)b * DIMN + l * 16;
    float na = 0.f;
    #pragma unroll
    for (int i = 0; i < 4; ++i) {
      float4 a = *(const float4*)(hp + i * 4);
      na = fmaf(a.x, a.x, na); na = fmaf(a.y, a.y, na);
      na = fmaf(a.z, a.z, na); na = fmaf(a.w, a.w, na);
    }
    N = wave_allsum(na);
  }
  float d[8];
  {
    float4 p0 = *(const float4*)(P + (size_t)b * 512 + l * 8);
    float4 p1 = *(const float4*)(P + (size_t)b * 512 + l * 8 + 4);
    d[0]=p0.x; d[1]=p0.y; d[2]=p0.z; d[3]=p0.w;
    d[4]=p1.x; d[5]=p1.y; d[6]=p1.z; d[7]=p1.w;
  }
  float gd[8];
  #pragma unroll
  for (int j = 0; j < 8; ++j)
    gd[j] = (float)Gb[(size_t)(l * 8 + j) * T_STEPS + (l * 8 + j)];
  f16x8 grow[8];
  #pragma unroll
  for (int j = 0; j < 8; ++j)
    grow[j] = *(const f16x8*)(Gb + (size_t)j * T_STEPS + l * 8);

  float c = 1.f, ic = 1.f, kk = 1.f / DIMN;
  if (SHIFT && l == 0) Sarr[(size_t)b * 512] = 1.f;
  float ccap = 1.f, iccap = 1.f;

  for (int tb = 0; tb < T_STEPS; tb += 8) {
    const int a = tb >> 3;               // lane holding slots tb..tb+7
    #pragma unroll
    for (int J = 0; J < 8; ++J) {
      const int t = tb + J;
      f16x8 g = grow[J];
      int tn = t + 8; if (tn > T_STEPS - 1) tn = T_STEPS - 1;
      grow[J] = *(const f16x8*)(Gb + (size_t)tn * T_STEPS + l * 8);
      const float e   = __int_as_float(__builtin_amdgcn_readlane(__float_as_int(d[J]),  a));
      const float gtt = __int_as_float(__builtin_amdgcn_readlane(__float_as_int(gd[J]), a));
      const float cold = c;
      #pragma unroll
      for (int j2 = 0; j2 < 8; ++j2) d[j2] = fmaf(cold, (float)g[j2], d[j2]);
      N = fmaf(2.f * cold, e, fmaf(cold * cold, gtt, N));
      const float m   = fmaf(N, kk, 1e-6f);
      const float rho = __builtin_amdgcn_rsqf(m);
      c  = cold * (m * rho);
      ic = ic * rho;
      kk = kk * (rho * rho);
      ccap  = (l == J) ? cold : ccap;
      iccap = (l == J) ? ic   : iccap;
    }
    if (l < 8) {
      Carr[(size_t)b * 512 + tb + l] = ccap;
      const int sidx = tb + SHIFT + l;
      if (sidx < T_STEPS) Sarr[(size_t)b * 512 + sidx] = iccap;
    }
  }
}

// ---------- recombine pass 0: G0[t+1] = u_{t+1} = h0 + sum_{s<=t} c_s w_s ; G0[0]=h0 ----------
__global__ __launch_bounds__(64) void recombine0(
    const f16* __restrict__ Wx, const float* __restrict__ h0,
    const float* __restrict__ Carr, f16* __restrict__ G0) {
  const int b = blockIdx.x, dc = blockIdx.y, l = threadIdx.x;
  const size_t base = (size_t)b * DIMN + dc * 128 + l * 2;
  float u0 = h0[base], u1 = h0[base + 1];
  *(f16x2*)(G0 + base) = pkrtz(u0, u1);
  f16x2 wbuf[8];
  #pragma unroll
  for (int j = 0; j < 8; ++j) wbuf[j] = *(const f16x2*)(Wx + (size_t)j * BD + base);
  const float* Cb = Carr + (size_t)b * 512;
  for (int tb = 0; tb < T_STEPS; tb += 8) {
    float4 ca = *(const float4*)(Cb + tb);
    float4 cz = *(const float4*)(Cb + tb + 4);
    const float cc[8] = {ca.x, ca.y, ca.z, ca.w, cz.x, cz.y, cz.z, cz.w};
    #pragma unroll
    for (int J = 0; J < 8; ++J) {
      const int t = tb + J;
      f16x2 w = wbuf[J];
      int tn = t + 8; if (tn > T_STEPS - 1) tn = T_STEPS - 1;
      wbuf[J] = *(const f16x2*)(Wx + (size_t)tn * BD + base);
      u0 = fmaf(cc[J], (float)w[0], u0);
      u1 = fmaf(cc[J], (float)w[1], u1);
      if (t < T_STEPS - 1)
        *(f16x2*)(G0 + (size_t)(t + 1) * BD + base) = pkrtz(u0, u1);
    }
  }
}

// ---------- recombine pass 1 + expand: v = ic_{t+1}*u_{t+1}; outs=v^2*sig(v); hout[t+1]=v ----------
__global__ __launch_bounds__(64) void recombine1_expand(
    const f16* __restrict__ Cin, const float* __restrict__ h0,
    const float* __restrict__ Carr, const float* __restrict__ Sarr,
    float* __restrict__ outs, float* __restrict__ hout) {
  const int b = blockIdx.x, dc = blockIdx.y, l = threadIdx.x;
  if (dc == 8) {                        // tail: hout[0] = h0
    const size_t o = (size_t)b * DIMN + (size_t)l * 16;
    #pragma unroll
    for (int i = 0; i < 4; ++i) {
      float4 a = *(const float4*)(h0 + o + i * 4);
      *(float4*)(hout + o + i * 4) = a;
    }
    return;
  }
  const size_t base = (size_t)b * DIMN + dc * 128 + l * 2;
  float u0 = h0[base], u1 = h0[base + 1];
  f16x2 wbuf[8];
  #pragma unroll
  for (int j = 0; j < 8; ++j) wbuf[j] = *(const f16x2*)(Cin + (size_t)j * BD + base);
  const float* Cb = Carr + (size_t)b * 512;
  const float* Sb = Sarr + (size_t)b * 512;
  for (int tb = 0; tb < T_STEPS; tb += 8) {
    float4 ca = *(const float4*)(Cb + tb);
    float4 cz = *(const float4*)(Cb + tb + 4);
    float4 sa = *(const float4*)(Sb + tb);
    float4 sz = *(const float4*)(Sb + tb + 4);
    const float cc[8] = {ca.x, ca.y, ca.z, ca.w, cz.x, cz.y, cz.z, cz.w};
    const float ss[8] = {sa.x, sa.y, sa.z, sa.w, sz.x, sz.y, sz.z, sz.w};
    #pragma unroll
    for (int J = 0; J < 8; ++J) {
      const int t = tb + J;
      f16x2 w = wbuf[J];
      int tn = t + 8; if (tn > T_STEPS - 1) tn = T_STEPS - 1;
      wbuf[J] = *(const f16x2*)(Cin + (size_t)tn * BD + base);
      u0 = fmaf(cc[J], (float)w[0], u0);
      u1 = fmaf(cc[J], (float)w[1], u1);
      const float v0 = ss[J] * u0, v1 = ss[J] * u1;
      const float o0 = v0 * v0 / (1.f + expf(-v0));
      const float o1 = v1 * v1 / (1.f + expf(-v1));
      *(float2*)(outs + (size_t)t * BD + base) = make_float2(o0, o1);
      *(float2*)(hout + (size_t)(t + 1) * BD + base) = make_float2(v0, v1);
    }
  }
}

extern "C" void kernel_launch(void* const* d_in, const int* in_sizes, int n_in,
                              void* d_out, int out_size, void* d_ws, size_t ws_size,
                              hipStream_t stream) {
  const float* x    = (const float*)d_in[0];
  const float* h0   = (const float*)d_in[1];
  const float* W    = (const float*)d_in[2];
  const float* Wh   = (const float*)d_in[3];
  const float* bias = (const float*)d_in[4];
  const float* la   = (const float*)d_in[5];
  const float* lb   = (const float*)d_in[6];

  char* ws = (char*)d_ws;
  f16* XH   = (f16*)(ws);                       // 32MB; dead after GEMM0
  f16* GRAM = (f16*)(ws);                       // 16.78MB, reuses XH slot
  f16* W16  = (f16*)(ws + 33554432ull);         // 2MB; dead after GEMM0
  f16* WH16 = (f16*)(ws + 35651584ull);         // 2MB; dead after GEMM1
  f16* WX16 = (f16*)(ws + 37748736ull);         // 32MB
  f16* G0   = (f16*)(ws + 71303168ull);         // 32MB
  f16* C16  = (f16*)(ws + 104857600ull);        // 32MB
  // scalar arrays in dead weight slots (64KB each)
  float* S0 = (float*)(ws + 33554432ull);
  float* C0 = (float*)(ws + 33554432ull + 65536ull);
  float* P0 = (float*)(ws + 33554432ull + 131072ull);
  float* S1 = (float*)(ws + 35651584ull);
  float* C1 = (float*)(ws + 35651584ull + 65536ull);
  float* P1 = (float*)(ws + 35651584ull + 131072ull);

  float* outs = (float*)d_out;
  float* hout = outs + (size_t)T_STEPS * BD;

  cvt_f32_f16<<<dim3((MROWS * DIMN / 8) / 256), 256, 0, stream>>>(x, XH, MROWS * DIMN / 8);
  cvt_f32_f16<<<dim3((DIMN * DIMN / 8) / 256), 256, 0, stream>>>(W, W16, DIMN * DIMN / 8);
  cvt_f32_f16<<<dim3((DIMN * DIMN / 8) / 256), 256, 0, stream>>>(Wh, WH16, DIMN * DIMN / 8);

  // WX16 = alpha * (x @ W^T + b)
  gemm_bt_f16<<<dim3(MROWS / 128, DIMN / 128), 256, 0, stream>>>(
      XH, W16, bias, WX16, la, lb, nullptr, nullptr, 0);

  // pass 0: Gram of WX16, P0 = h0.w, scalar scan, recombine
  gram_f16<<<dim3(4, 4, BATCH), 256, 0, stream>>>(WX16, GRAM);
  gemv_p<<<dim3(BATCH, 8), 256, 0, stream>>>(WX16, h0, P0);
  scalar_scan<1><<<dim3(BATCH), 64, 0, stream>>>(GRAM, P0, h0, C0, S0);
  recombine0<<<dim3(BATCH, 8), 64, 0, stream>>>(WX16, h0, C0, G0);

  // C16 = WX16 + beta * ic0[row] * (G0 @ Wh^T)
  gemm_bt_f16<<<dim3(MROWS / 128, DIMN / 128), 256, 0, stream>>>(
      G0, WH16, nullptr, C16, la, lb, S0, WX16, 1);

  // pass 1: Gram of C16, P1, scalar scan, recombine + expand (fused)
  gram_f16<<<dim3(4, 4, BATCH), 256, 0, stream>>>(C16, GRAM);
  gemv_p<<<dim3(BATCH, 8), 256, 0, stream>>>(C16, h0, P1);
  scalar_scan<0><<<dim3(BATCH), 64, 0, stream>>>(GRAM, P1, h0, C1, S1);
  recombine1_expand<<<dim3(BATCH, 9), 64, 0, stream>>>(C16, h0, C1, S1, outs, hout);
}

// Round 7
// 572.935 us; speedup vs baseline: 1.0927x; 1.0927x over previous
//
#include <hip/hip_runtime.h>
#include <stdint.h>

#define T_STEPS 512
#define BATCH   32
#define DIMN    1024
#define MROWS   (T_STEPS*BATCH)   // 16384
#define BD      (BATCH*DIMN)      // 32768

typedef _Float16 f16;
typedef _Float16 f16x8 __attribute__((ext_vector_type(8)));
typedef _Float16 f16x4 __attribute__((ext_vector_type(4)));
typedef _Float16 f16x2 __attribute__((ext_vector_type(2)));
typedef float    f32x4 __attribute__((ext_vector_type(4)));

union U8 { f16x8 v; f16x2 p[4]; };
union U4 { f16x4 v; f16x2 p[2]; };

// packed f32x2 -> f16x2 (RTZ)
__device__ __forceinline__ f16x2 pkrtz(float a, float b) {
  return __builtin_bit_cast(f16x2, __builtin_amdgcn_cvt_pkrtz(a, b));
}

// ---------- async global -> LDS, 16 B per lane ----------
__device__ __forceinline__ void load16_to_lds(const f16* gptr, f16* lptr) {
  __builtin_amdgcn_global_load_lds(
      (const __attribute__((address_space(1))) unsigned int*)(uintptr_t)gptr,
      (__attribute__((address_space(3))) unsigned int*)(uint32_t)(uintptr_t)lptr,
      16, 0, 0);
}

// ---------- DPP row-rotate add ----------
template<int CTRL>
__device__ __forceinline__ float dpp_ror_add(float v) {
  int iv = __float_as_int(v);
  int rv = __builtin_amdgcn_update_dpp(iv, iv, CTRL, 0xF, 0xF, false);
  return v + __int_as_float(rv);
}

// all-lanes sum of 64 lanes
__device__ __forceinline__ float wave_allsum(float s) {
  s = dpp_ror_add<0x128>(s);   // row_ror:8
  s = dpp_ror_add<0x124>(s);   // row_ror:4
  s = dpp_ror_add<0x122>(s);   // row_ror:2
  s = dpp_ror_add<0x121>(s);   // row_ror:1
  float a = __int_as_float(__builtin_amdgcn_readlane(__float_as_int(s), 0));
  float b = __int_as_float(__builtin_amdgcn_readlane(__float_as_int(s), 16));
  float c = __int_as_float(__builtin_amdgcn_readlane(__float_as_int(s), 32));
  float d = __int_as_float(__builtin_amdgcn_readlane(__float_as_int(s), 48));
  return (a + b) + (c + d);
}

// ---------- f32 -> f16 convert, 8 elems/thread ----------
__global__ __launch_bounds__(256) void cvt_f32_f16(const float* __restrict__ src,
                                                   f16* __restrict__ dst, int n8) {
  int i = blockIdx.x * 256 + threadIdx.x;
  if (i >= n8) return;
  const float4* s = (const float4*)src;
  float4 a = s[2*i], b = s[2*i + 1];
  f16x8 o = { (f16)a.x, (f16)a.y, (f16)a.z, (f16)a.w,
              (f16)b.x, (f16)b.y, (f16)b.z, (f16)b.w };
  *(f16x8*)(dst + (size_t)i * 8) = o;
}

// ---------- 128x128-tile fp16 MFMA GEMM (verified) ----------
// mode 0: Cout = (f16)( exp(la)      * (acc + bias[n]) )
// mode 1: Cout = (f16)( addend[m,n] + 0.1*sigmoid(lb)*rowscale_bmajor[m]*acc )
//   rowscale layout (mode 1): S[b][t], stride 512  (row m = t*BATCH + b)
__global__ __launch_bounds__(256) void gemm_bt_f16(
    const f16* __restrict__ A, const f16* __restrict__ B,
    const float* __restrict__ bias, f16* __restrict__ Cout,
    const float* __restrict__ la, const float* __restrict__ lb,
    const float* __restrict__ rowscale, const f16* __restrict__ addend, int mode) {
  constexpr int K = DIMN;
  constexpr int N = DIMN;
  __shared__ f16 Alds[128 * 32];
  __shared__ f16 Blds[128 * 32];
  const int tid  = threadIdx.x;
  const int lane = tid & 63;
  const int wid  = tid >> 6;
  const int wm = wid & 1, wn = wid >> 1;
  const int l15  = lane & 15;
  const int quad = lane >> 4;
  const int swz  = (l15 >> 1) & 3;
  const int rowBase = blockIdx.x * 128;
  const int colBase = blockIdx.y * 128;
  const int sr = lane >> 2;
  const int cs = lane & 3;

  const float scale = (mode == 0) ? expf(la[0])
                                  : 0.1f / (1.0f + expf(-lb[0]));

  f32x4 acc[4][4] = {};

  for (int k0 = 0; k0 < K; k0 += 32) {
    #pragma unroll
    for (int i = 0; i < 2; ++i) {
      const int g = wid + i * 4;
      const int r = g * 16 + sr;
      const int cd = cs ^ ((r >> 1) & 3);
      load16_to_lds(A + (size_t)(rowBase + r) * K + k0 + cd * 8, Alds + g * 512);
      load16_to_lds(B + (size_t)(colBase + r) * K + k0 + cd * 8, Blds + g * 512);
    }
    __syncthreads();
    f16x8 af[4], bf[4];
    #pragma unroll
    for (int mi = 0; mi < 4; ++mi) {
      const int r = wm * 64 + mi * 16 + l15;
      af[mi] = *(const f16x8*)(Alds + r * 32 + (quad ^ swz) * 8);
    }
    #pragma unroll
    for (int ni = 0; ni < 4; ++ni) {
      const int r = wn * 64 + ni * 16 + l15;
      bf[ni] = *(const f16x8*)(Blds + r * 32 + (quad ^ swz) * 8);
    }
    #pragma unroll
    for (int mi = 0; mi < 4; ++mi)
      #pragma unroll
      for (int ni = 0; ni < 4; ++ni)
        acc[mi][ni] = __builtin_amdgcn_mfma_f32_16x16x32_f16(af[mi], bf[ni], acc[mi][ni], 0, 0, 0);
    __syncthreads();
  }

  float colb[4];
  #pragma unroll
  for (int ni = 0; ni < 4; ++ni)
    colb[ni] = (mode == 0) ? bias[colBase + wn * 64 + ni * 16 + l15] : 0.0f;

  #pragma unroll
  for (int mi = 0; mi < 4; ++mi) {
    const int m0 = rowBase + wm * 64 + mi * 16 + quad * 4;
    #pragma unroll
    for (int j = 0; j < 4; ++j) {
      const size_t row = (size_t)(m0 + j);
      const float rs = (mode == 0)
          ? scale
          : scale * rowscale[(((int)row & 31) << 9) | ((int)row >> 5)];
      #pragma unroll
      for (int ni = 0; ni < 4; ++ni) {
        const int n = colBase + wn * 64 + ni * 16 + l15;
        float v;
        if (mode == 0) v = rs * (acc[mi][ni][j] + colb[ni]);
        else           v = fmaf(rs, acc[mi][ni][j], (float)addend[row * N + n]);
        Cout[row * N + n] = (f16)v;
      }
    }
  }
}

// ---------- batched Gram: Gout[b][t][s] = w_t . w_s  (upper-triangle tiles only) ----------
__global__ __launch_bounds__(256) void gram_f16(
    const f16* __restrict__ A, f16* __restrict__ Gout) {
  const int bx = blockIdx.x, by = blockIdx.y, bz = blockIdx.z;
  if (by < bx) return;
  __shared__ f16 Alds[128 * 32];
  __shared__ f16 Blds[128 * 32];
  const int tid  = threadIdx.x;
  const int lane = tid & 63;
  const int wid  = tid >> 6;
  const int wm = wid & 1, wn = wid >> 1;
  const int l15  = lane & 15;
  const int quad = lane >> 4;
  const int swz  = (l15 >> 1) & 3;
  const int rowBase = bx * 128;
  const int colBase = by * 128;
  const int sr = lane >> 2;
  const int cs = lane & 3;
  const f16* Ab = A + (size_t)bz * DIMN;

  f32x4 acc[4][4] = {};

  for (int k0 = 0; k0 < DIMN; k0 += 32) {
    #pragma unroll
    for (int i = 0; i < 2; ++i) {
      const int g = wid + i * 4;
      const int r = g * 16 + sr;
      const int cd = cs ^ ((r >> 1) & 3);
      load16_to_lds(Ab + (size_t)(rowBase + r) * BD + k0 + cd * 8, Alds + g * 512);
      load16_to_lds(Ab + (size_t)(colBase + r) * BD + k0 + cd * 8, Blds + g * 512);
    }
    __syncthreads();
    f16x8 af[4], bf[4];
    #pragma unroll
    for (int mi = 0; mi < 4; ++mi) {
      const int r = wm * 64 + mi * 16 + l15;
      af[mi] = *(const f16x8*)(Alds + r * 32 + (quad ^ swz) * 8);
    }
    #pragma unroll
    for (int ni = 0; ni < 4; ++ni) {
      const int r = wn * 64 + ni * 16 + l15;
      bf[ni] = *(const f16x8*)(Blds + r * 32 + (quad ^ swz) * 8);
    }
    #pragma unroll
    for (int mi = 0; mi < 4; ++mi)
      #pragma unroll
      for (int ni = 0; ni < 4; ++ni)
        acc[mi][ni] = __builtin_amdgcn_mfma_f32_16x16x32_f16(af[mi], bf[ni], acc[mi][ni], 0, 0, 0);
    __syncthreads();
  }

  f16* Gb = Gout + (size_t)bz * (T_STEPS * T_STEPS);
  #pragma unroll
  for (int mi = 0; mi < 4; ++mi) {
    const int m0 = rowBase + wm * 64 + mi * 16 + quad * 4;
    #pragma unroll
    for (int j = 0; j < 4; ++j) {
      #pragma unroll
      for (int ni = 0; ni < 4; ++ni) {
        const int n = colBase + wn * 64 + ni * 16 + l15;
        Gb[(size_t)(m0 + j) * T_STEPS + n] = (f16)acc[mi][ni][j];
      }
    }
  }
}

// ---------- P[b][s] = h0[b] . w_s ----------
__global__ __launch_bounds__(256) void gemv_p(
    const f16* __restrict__ Wm, const float* __restrict__ h0,
    float* __restrict__ P) {
  const int b = blockIdx.x, sg = blockIdx.y;
  const int w = threadIdx.x >> 6, l = threadIdx.x & 63;
  float h[16];
  {
    const float* hp = h0 + (size_t)b * DIMN + l * 16;
    #pragma unroll
    for (int i = 0; i < 4; ++i) {
      float4 a = *(const float4*)(hp + i * 4);
      h[i*4+0] = a.x; h[i*4+1] = a.y; h[i*4+2] = a.z; h[i*4+3] = a.w;
    }
  }
  for (int k = 0; k < 16; ++k) {
    const int s = sg * 64 + w * 16 + k;
    const f16* wp = Wm + (size_t)s * BD + (size_t)b * DIMN + l * 16;
    f16x8 a0 = *(const f16x8*)(wp);
    f16x8 a1 = *(const f16x8*)(wp + 8);
    float acc = 0.f;
    #pragma unroll
    for (int i = 0; i < 8; ++i) acc = fmaf((float)a0[i], h[i], acc);
    #pragma unroll
    for (int i = 0; i < 8; ++i) acc = fmaf((float)a1[i], h[i+8], acc);
    acc = wave_allsum(acc);
    if (l == 0) P[(size_t)b * 512 + s] = acc;
  }
}

// ---------- scalar scan: the sequential chain, D-free (verified round 6) ----------
template<int SHIFT>
__global__ __launch_bounds__(64, 1) void scalar_scan(
    const f16* __restrict__ Gm, const float* __restrict__ P,
    const float* __restrict__ h0,
    float* __restrict__ Carr, float* __restrict__ Sarr) {
  const int b = blockIdx.x, l = threadIdx.x;
  const f16* Gb = Gm + (size_t)b * (T_STEPS * T_STEPS);
  float N;
  {
    const float* hp = h0 + (size_t)b * DIMN + l * 16;
    float na = 0.f;
    #pragma unroll
    for (int i = 0; i < 4; ++i) {
      float4 a = *(const float4*)(hp + i * 4);
      na = fmaf(a.x, a.x, na); na = fmaf(a.y, a.y, na);
      na = fmaf(a.z, a.z, na); na = fmaf(a.w, a.w, na);
    }
    N = wave_allsum(na);
  }
  float d[8];
  {
    float4 p0 = *(const float4*)(P + (size_t)b * 512 + l * 8);
    float4 p1 = *(const float4*)(P + (size_t)b * 512 + l * 8 + 4);
    d[0]=p0.x; d[1]=p0.y; d[2]=p0.z; d[3]=p0.w;
    d[4]=p1.x; d[5]=p1.y; d[6]=p1.z; d[7]=p1.w;
  }
  float gd[8];
  #pragma unroll
  for (int j = 0; j < 8; ++j)
    gd[j] = (float)Gb[(size_t)(l * 8 + j) * T_STEPS + (l * 8 + j)];
  f16x8 grow[8];
  #pragma unroll
  for (int j = 0; j < 8; ++j)
    grow[j] = *(const f16x8*)(Gb + (size_t)j * T_STEPS + l * 8);

  float c = 1.f, ic = 1.f, kk = 1.f / DIMN;
  if (SHIFT && l == 0) Sarr[(size_t)b * 512] = 1.f;
  float ccap = 1.f, iccap = 1.f;

  for (int tb = 0; tb < T_STEPS; tb += 8) {
    const int a = tb >> 3;
    #pragma unroll
    for (int J = 0; J < 8; ++J) {
      const int t = tb + J;
      f16x8 g = grow[J];
      int tn = t + 8; if (tn > T_STEPS - 1) tn = T_STEPS - 1;
      grow[J] = *(const f16x8*)(Gb + (size_t)tn * T_STEPS + l * 8);
      const float e   = __int_as_float(__builtin_amdgcn_readlane(__float_as_int(d[J]),  a));
      const float gtt = __int_as_float(__builtin_amdgcn_readlane(__float_as_int(gd[J]), a));
      const float cold = c;
      #pragma unroll
      for (int j2 = 0; j2 < 8; ++j2) d[j2] = fmaf(cold, (float)g[j2], d[j2]);
      N = fmaf(2.f * cold, e, fmaf(cold * cold, gtt, N));
      const float m   = fmaf(N, kk, 1e-6f);
      const float rho = __builtin_amdgcn_rsqf(m);
      c  = cold * (m * rho);
      ic = ic * rho;
      kk = kk * (rho * rho);
      ccap  = (l == J) ? cold : ccap;
      iccap = (l == J) ? ic   : iccap;
    }
    if (l < 8) {
      Carr[(size_t)b * 512 + tb + l] = ccap;
      const int sidx = tb + SHIFT + l;
      if (sidx < T_STEPS) Sarr[(size_t)b * 512 + sidx] = iccap;
    }
  }
}

// ---------- phase A: PS[tc][b][d] = sum_{t in chunk tc} c_t * w_t[b][d] ----------
__global__ __launch_bounds__(64) void chunk_partial(
    const f16* __restrict__ Win, const float* __restrict__ Carr,
    float* __restrict__ PS) {
  const int b = blockIdx.x, dcy = blockIdx.y, tc = blockIdx.z;
  const int l = threadIdx.x;
  const size_t base = (size_t)b * DIMN + dcy * 256 + l * 4;
  const float* Cb = Carr + (size_t)b * 512;
  const int t0 = tc * 64;
  float a0 = 0.f, a1 = 0.f, a2 = 0.f, a3 = 0.f;
  f16x4 ring[8];
  #pragma unroll
  for (int j = 0; j < 8; ++j)
    ring[j] = *(const f16x4*)(Win + (size_t)(t0 + j) * BD + base);
  for (int tt = 0; tt < 64; tt += 8) {
    float4 ca = *(const float4*)(Cb + t0 + tt);
    float4 cz = *(const float4*)(Cb + t0 + tt + 4);
    const float cc[8] = {ca.x, ca.y, ca.z, ca.w, cz.x, cz.y, cz.z, cz.w};
    #pragma unroll
    for (int J = 0; J < 8; ++J) {
      f16x4 w = ring[J];
      int tn = t0 + tt + J + 8; if (tn > T_STEPS - 1) tn = T_STEPS - 1;
      ring[J] = *(const f16x4*)(Win + (size_t)tn * BD + base);
      a0 = fmaf(cc[J], (float)w[0], a0);
      a1 = fmaf(cc[J], (float)w[1], a1);
      a2 = fmaf(cc[J], (float)w[2], a2);
      a3 = fmaf(cc[J], (float)w[3], a3);
    }
  }
  *(float4*)(PS + (size_t)tc * BD + base) = make_float4(a0, a1, a2, a3);
}

// ---------- phase B pass 0: G0[t+1] = u_{t+1}; G0[0] = h0 ----------
__global__ __launch_bounds__(64) void recomb0B(
    const f16* __restrict__ Wx, const float* __restrict__ h0,
    const float* __restrict__ Carr, const float* __restrict__ PS,
    f16* __restrict__ G0) {
  const int b = blockIdx.x, dcy = blockIdx.y, tc = blockIdx.z;
  const int l = threadIdx.x;
  const size_t base = (size_t)b * DIMN + dcy * 256 + l * 4;
  float4 h = *(const float4*)(h0 + base);
  float u0 = h.x, u1 = h.y, u2 = h.z, u3 = h.w;
  for (int p = 0; p < tc; ++p) {
    float4 ps = *(const float4*)(PS + (size_t)p * BD + base);
    u0 += ps.x; u1 += ps.y; u2 += ps.z; u3 += ps.w;
  }
  if (tc == 0) {
    U4 g; g.p[0] = pkrtz(u0, u1); g.p[1] = pkrtz(u2, u3);
    *(f16x4*)(G0 + base) = g.v;
  }
  const float* Cb = Carr + (size_t)b * 512;
  const int t0 = tc * 64;
  f16x4 ring[8];
  #pragma unroll
  for (int j = 0; j < 8; ++j)
    ring[j] = *(const f16x4*)(Wx + (size_t)(t0 + j) * BD + base);
  for (int tt = 0; tt < 64; tt += 8) {
    float4 ca = *(const float4*)(Cb + t0 + tt);
    float4 cz = *(const float4*)(Cb + t0 + tt + 4);
    const float cc[8] = {ca.x, ca.y, ca.z, ca.w, cz.x, cz.y, cz.z, cz.w};
    #pragma unroll
    for (int J = 0; J < 8; ++J) {
      const int t = t0 + tt + J;
      f16x4 w = ring[J];
      int tn = t + 8; if (tn > T_STEPS - 1) tn = T_STEPS - 1;
      ring[J] = *(const f16x4*)(Wx + (size_t)tn * BD + base);
      u0 = fmaf(cc[J], (float)w[0], u0);
      u1 = fmaf(cc[J], (float)w[1], u1);
      u2 = fmaf(cc[J], (float)w[2], u2);
      u3 = fmaf(cc[J], (float)w[3], u3);
      if (t < T_STEPS - 1) {
        U4 g; g.p[0] = pkrtz(u0, u1); g.p[1] = pkrtz(u2, u3);
        *(f16x4*)(G0 + (size_t)(t + 1) * BD + base) = g.v;
      }
    }
  }
}

// ---------- phase B pass 1 + expand ----------
__global__ __launch_bounds__(64) void recomb1B(
    const f16* __restrict__ Cin, const float* __restrict__ h0,
    const float* __restrict__ Carr, const float* __restrict__ Sarr,
    const float* __restrict__ PS,
    float* __restrict__ outs, float* __restrict__ hout) {
  const int b = blockIdx.x, dcy = blockIdx.y, tc = blockIdx.z;
  const int l = threadIdx.x;
  const size_t base = (size_t)b * DIMN + dcy * 256 + l * 4;
  if (tc == 8) {                        // tail: hout[0] = h0
    float4 a = *(const float4*)(h0 + base);
    *(float4*)(hout + base) = a;
    return;
  }
  float4 h = *(const float4*)(h0 + base);
  float u0 = h.x, u1 = h.y, u2 = h.z, u3 = h.w;
  for (int p = 0; p < tc; ++p) {
    float4 ps = *(const float4*)(PS + (size_t)p * BD + base);
    u0 += ps.x; u1 += ps.y; u2 += ps.z; u3 += ps.w;
  }
  const float* Cb = Carr + (size_t)b * 512;
  const float* Sb = Sarr + (size_t)b * 512;
  const int t0 = tc * 64;
  f16x4 ring[8];
  #pragma unroll
  for (int j = 0; j < 8; ++j)
    ring[j] = *(const f16x4*)(Cin + (size_t)(t0 + j) * BD + base);
  for (int tt = 0; tt < 64; tt += 8) {
    float4 ca = *(const float4*)(Cb + t0 + tt);
    float4 cz = *(const float4*)(Cb + t0 + tt + 4);
    float4 sa = *(const float4*)(Sb + t0 + tt);
    float4 sz = *(const float4*)(Sb + t0 + tt + 4);
    const float cc[8] = {ca.x, ca.y, ca.z, ca.w, cz.x, cz.y, cz.z, cz.w};
    const float ss[8] = {sa.x, sa.y, sa.z, sa.w, sz.x, sz.y, sz.z, sz.w};
    #pragma unroll
    for (int J = 0; J < 8; ++J) {
      const int t = t0 + tt + J;
      f16x4 w = ring[J];
      int tn = t + 8; if (tn > T_STEPS - 1) tn = T_STEPS - 1;
      ring[J] = *(const f16x4*)(Cin + (size_t)tn * BD + base);
      u0 = fmaf(cc[J], (float)w[0], u0);
      u1 = fmaf(cc[J], (float)w[1], u1);
      u2 = fmaf(cc[J], (float)w[2], u2);
      u3 = fmaf(cc[J], (float)w[3], u3);
      const float v0 = ss[J] * u0, v1 = ss[J] * u1;
      const float v2 = ss[J] * u2, v3 = ss[J] * u3;
      const float o0 = v0 * v0 / (1.f + expf(-v0));
      const float o1 = v1 * v1 / (1.f + expf(-v1));
      const float o2 = v2 * v2 / (1.f + expf(-v2));
      const float o3 = v3 * v3 / (1.f + expf(-v3));
      *(float4*)(outs + (size_t)t * BD + base) = make_float4(o0, o1, o2, o3);
      *(float4*)(hout + (size_t)(t + 1) * BD + base) = make_float4(v0, v1, v2, v3);
    }
  }
}

extern "C" void kernel_launch(void* const* d_in, const int* in_sizes, int n_in,
                              void* d_out, int out_size, void* d_ws, size_t ws_size,
                              hipStream_t stream) {
  const float* x    = (const float*)d_in[0];
  const float* h0   = (const float*)d_in[1];
  const float* W    = (const float*)d_in[2];
  const float* Wh   = (const float*)d_in[3];
  const float* bias = (const float*)d_in[4];
  const float* la   = (const float*)d_in[5];
  const float* lb   = (const float*)d_in[6];

  char* ws = (char*)d_ws;
  f16* XH   = (f16*)(ws);                       // 32MB; dead after GEMM0
  f16* GRAM = (f16*)(ws);                       // 16.78MB, reuses XH slot
  f16* W16  = (f16*)(ws + 33554432ull);         // 2MB; dead after GEMM0
  f16* WH16 = (f16*)(ws + 35651584ull);         // 2MB; dead after GEMM1
  f16* WX16 = (f16*)(ws + 37748736ull);         // 32MB
  f16* G0   = (f16*)(ws + 71303168ull);         // 32MB
  f16* C16  = (f16*)(ws + 104857600ull);        // 32MB
  // scalar arrays + chunk partials in dead weight slots
  float* S0  = (float*)(ws + 33554432ull);
  float* C0  = (float*)(ws + 33554432ull + 65536ull);
  float* P0  = (float*)(ws + 33554432ull + 131072ull);
  float* PS0 = (float*)(ws + 33554432ull + 196608ull);   // 1MB, W16 slot
  float* S1  = (float*)(ws + 35651584ull);
  float* C1  = (float*)(ws + 35651584ull + 65536ull);
  float* P1  = (float*)(ws + 35651584ull + 131072ull);
  float* PS1 = (float*)(ws + 35651584ull + 196608ull);   // 1MB, WH16 slot

  float* outs = (float*)d_out;
  float* hout = outs + (size_t)T_STEPS * BD;

  cvt_f32_f16<<<dim3((MROWS * DIMN / 8) / 256), 256, 0, stream>>>(x, XH, MROWS * DIMN / 8);
  cvt_f32_f16<<<dim3((DIMN * DIMN / 8) / 256), 256, 0, stream>>>(W, W16, DIMN * DIMN / 8);
  cvt_f32_f16<<<dim3((DIMN * DIMN / 8) / 256), 256, 0, stream>>>(Wh, WH16, DIMN * DIMN / 8);

  // WX16 = alpha * (x @ W^T + b)
  gemm_bt_f16<<<dim3(MROWS / 128, DIMN / 128), 256, 0, stream>>>(
      XH, W16, bias, WX16, la, lb, nullptr, nullptr, 0);

  // pass 0: Gram, P0, scalar chain, chunked recombine
  gram_f16<<<dim3(4, 4, BATCH), 256, 0, stream>>>(WX16, GRAM);
  gemv_p<<<dim3(BATCH, 8), 256, 0, stream>>>(WX16, h0, P0);
  scalar_scan<1><<<dim3(BATCH), 64, 0, stream>>>(GRAM, P0, h0, C0, S0);
  chunk_partial<<<dim3(BATCH, 4, 8), 64, 0, stream>>>(WX16, C0, PS0);
  recomb0B<<<dim3(BATCH, 4, 8), 64, 0, stream>>>(WX16, h0, C0, PS0, G0);

  // C16 = WX16 + beta * ic0[row] * (G0 @ Wh^T)
  gemm_bt_f16<<<dim3(MROWS / 128, DIMN / 128), 256, 0, stream>>>(
      G0, WH16, nullptr, C16, la, lb, S0, WX16, 1);

  // pass 1: Gram, P1, scalar chain, chunked recombine + expand (fused)
  gram_f16<<<dim3(4, 4, BATCH), 256, 0, stream>>>(C16, GRAM);
  gemv_p<<<dim3(BATCH, 8), 256, 0, stream>>>(C16, h0, P1);
  scalar_scan<0><<<dim3(BATCH), 64, 0, stream>>>(GRAM, P1, h0, C1, S1);
  chunk_partial<<<dim3(BATCH, 4, 8), 64, 0, stream>>>(C16, C1, PS1);
  recomb1B<<<dim3(BATCH, 4, 9), 64, 0, stream>>>(C16, h0, C1, S1, PS1, outs, hout);
}

// Round 8
// 568.791 us; speedup vs baseline: 1.1007x; 1.0073x over previous
//
#include <hip/hip_runtime.h>
#include <stdint.h>

#define T_STEPS 512
#define BATCH   32
#define DIMN    1024
#define MROWS   (T_STEPS*BATCH)   // 16384
#define BD      (BATCH*DIMN)      // 32768

typedef _Float16 f16;
typedef _Float16 f16x8 __attribute__((ext_vector_type(8)));
typedef _Float16 f16x4 __attribute__((ext_vector_type(4)));
typedef _Float16 f16x2 __attribute__((ext_vector_type(2)));
typedef float    f32x4 __attribute__((ext_vector_type(4)));

union U8 { f16x8 v; f16x2 p[4]; };
union U4 { f16x4 v; f16x2 p[2]; };

// packed f32x2 -> f16x2 (RTZ)
__device__ __forceinline__ f16x2 pkrtz(float a, float b) {
  return __builtin_bit_cast(f16x2, __builtin_amdgcn_cvt_pkrtz(a, b));
}

// ---------- async global -> LDS, 16 B per lane ----------
__device__ __forceinline__ void load16_to_lds(const f16* gptr, f16* lptr) {
  __builtin_amdgcn_global_load_lds(
      (const __attribute__((address_space(1))) unsigned int*)(uintptr_t)gptr,
      (__attribute__((address_space(3))) unsigned int*)(uint32_t)(uintptr_t)lptr,
      16, 0, 0);
}

// ---------- DPP row-rotate add ----------
template<int CTRL>
__device__ __forceinline__ float dpp_ror_add(float v) {
  int iv = __float_as_int(v);
  int rv = __builtin_amdgcn_update_dpp(iv, iv, CTRL, 0xF, 0xF, false);
  return v + __int_as_float(rv);
}

// all-lanes sum of 64 lanes
__device__ __forceinline__ float wave_allsum(float s) {
  s = dpp_ror_add<0x128>(s);   // row_ror:8
  s = dpp_ror_add<0x124>(s);   // row_ror:4
  s = dpp_ror_add<0x122>(s);   // row_ror:2
  s = dpp_ror_add<0x121>(s);   // row_ror:1
  float a = __int_as_float(__builtin_amdgcn_readlane(__float_as_int(s), 0));
  float b = __int_as_float(__builtin_amdgcn_readlane(__float_as_int(s), 16));
  float c = __int_as_float(__builtin_amdgcn_readlane(__float_as_int(s), 32));
  float d = __int_as_float(__builtin_amdgcn_readlane(__float_as_int(s), 48));
  return (a + b) + (c + d);
}

// ---------- f32 -> f16 convert, 8 elems/thread ----------
__global__ __launch_bounds__(256) void cvt_f32_f16(const float* __restrict__ src,
                                                   f16* __restrict__ dst, int n8) {
  int i = blockIdx.x * 256 + threadIdx.x;
  if (i >= n8) return;
  const float4* s = (const float4*)src;
  float4 a = s[2*i], b = s[2*i + 1];
  f16x8 o = { (f16)a.x, (f16)a.y, (f16)a.z, (f16)a.w,
              (f16)b.x, (f16)b.y, (f16)b.z, (f16)b.w };
  *(f16x8*)(dst + (size_t)i * 8) = o;
}

// ---------- 128x128-tile fp16 MFMA GEMM, double-buffered LDS + counted vmcnt ----------
// Per K-step: stage tile k+1 (4 global_load_lds/lane), s_waitcnt vmcnt(4) (next tile's
// loads stay in flight), raw s_barrier (no vmcnt(0) drain), ds_read+MFMA, raw s_barrier.
// mode 0: Cout = (f16)( exp(la)      * (acc + bias[n]) )
// mode 1: Cout = (f16)( addend[m,n] + 0.1*sigmoid(lb)*rowscale_bmajor[m]*acc )
//   rowscale layout (mode 1): S[b][t], stride 512  (row m = t*BATCH + b)
__global__ __launch_bounds__(256) void gemm_bt_f16(
    const f16* __restrict__ A, const f16* __restrict__ B,
    const float* __restrict__ bias, f16* __restrict__ Cout,
    const float* __restrict__ la, const float* __restrict__ lb,
    const float* __restrict__ rowscale, const f16* __restrict__ addend, int mode) {
  constexpr int K = DIMN;
  constexpr int N = DIMN;
  __shared__ f16 Alds[2][128 * 32];
  __shared__ f16 Blds[2][128 * 32];
  const int tid  = threadIdx.x;
  const int lane = tid & 63;
  const int wid  = tid >> 6;
  const int wm = wid & 1, wn = wid >> 1;
  const int l15  = lane & 15;
  const int quad = lane >> 4;
  const int swz  = (l15 >> 1) & 3;
  const int rowBase = blockIdx.x * 128;
  const int colBase = blockIdx.y * 128;
  const int sr = lane >> 2;
  const int cs = lane & 3;

  const float scale = (mode == 0) ? expf(la[0])
                                  : 0.1f / (1.0f + expf(-lb[0]));

  f32x4 acc[4][4] = {};

#define GSTAGE(bi, k0)                                                          \
  { _Pragma("unroll")                                                           \
    for (int i_ = 0; i_ < 2; ++i_) {                                            \
      const int g_ = wid + i_ * 4;                                              \
      const int r_ = g_ * 16 + sr;                                              \
      const int cd_ = cs ^ ((r_ >> 1) & 3);                                     \
      load16_to_lds(A + (size_t)(rowBase + r_) * K + (k0) + cd_ * 8,            \
                    &Alds[bi][g_ * 512]);                                       \
      load16_to_lds(B + (size_t)(colBase + r_) * K + (k0) + cd_ * 8,            \
                    &Blds[bi][g_ * 512]);                                       \
    } }

  GSTAGE(0, 0);
  int cur = 0;
  for (int k0 = 0; k0 < K; k0 += 32, cur ^= 1) {
    if (k0 + 32 < K) {
      GSTAGE(cur ^ 1, k0 + 32);
      asm volatile("s_waitcnt vmcnt(4)" ::: "memory");
    } else {
      asm volatile("s_waitcnt vmcnt(0)" ::: "memory");
    }
    __builtin_amdgcn_s_barrier();
    asm volatile("" ::: "memory");
    f16x8 af[4], bf[4];
    #pragma unroll
    for (int mi = 0; mi < 4; ++mi) {
      const int r = wm * 64 + mi * 16 + l15;
      af[mi] = *(const f16x8*)(&Alds[cur][r * 32 + (quad ^ swz) * 8]);
    }
    #pragma unroll
    for (int ni = 0; ni < 4; ++ni) {
      const int r = wn * 64 + ni * 16 + l15;
      bf[ni] = *(const f16x8*)(&Blds[cur][r * 32 + (quad ^ swz) * 8]);
    }
    #pragma unroll
    for (int mi = 0; mi < 4; ++mi)
      #pragma unroll
      for (int ni = 0; ni < 4; ++ni)
        acc[mi][ni] = __builtin_amdgcn_mfma_f32_16x16x32_f16(af[mi], bf[ni], acc[mi][ni], 0, 0, 0);
    asm volatile("" ::: "memory");
    __builtin_amdgcn_s_barrier();
  }
#undef GSTAGE

  float colb[4];
  #pragma unroll
  for (int ni = 0; ni < 4; ++ni)
    colb[ni] = (mode == 0) ? bias[colBase + wn * 64 + ni * 16 + l15] : 0.0f;

  #pragma unroll
  for (int mi = 0; mi < 4; ++mi) {
    const int m0 = rowBase + wm * 64 + mi * 16 + quad * 4;
    #pragma unroll
    for (int j = 0; j < 4; ++j) {
      const size_t row = (size_t)(m0 + j);
      const float rs = (mode == 0)
          ? scale
          : scale * rowscale[(((int)row & 31) << 9) | ((int)row >> 5)];
      #pragma unroll
      for (int ni = 0; ni < 4; ++ni) {
        const int n = colBase + wn * 64 + ni * 16 + l15;
        float v;
        if (mode == 0) v = rs * (acc[mi][ni][j] + colb[ni]);
        else           v = fmaf(rs, acc[mi][ni][j], (float)addend[row * N + n]);
        Cout[row * N + n] = (f16)v;
      }
    }
  }
}

// ---------- batched Gram (same double-buffered loop; row stride BD) ----------
__global__ __launch_bounds__(256) void gram_f16(
    const f16* __restrict__ A, f16* __restrict__ Gout) {
  const int bx = blockIdx.x, by = blockIdx.y, bz = blockIdx.z;
  if (by < bx) return;
  __shared__ f16 Alds[2][128 * 32];
  __shared__ f16 Blds[2][128 * 32];
  const int tid  = threadIdx.x;
  const int lane = tid & 63;
  const int wid  = tid >> 6;
  const int wm = wid & 1, wn = wid >> 1;
  const int l15  = lane & 15;
  const int quad = lane >> 4;
  const int swz  = (l15 >> 1) & 3;
  const int rowBase = bx * 128;
  const int colBase = by * 128;
  const int sr = lane >> 2;
  const int cs = lane & 3;
  const f16* Ab = A + (size_t)bz * DIMN;

  f32x4 acc[4][4] = {};

#define GRSTAGE(bi, k0)                                                         \
  { _Pragma("unroll")                                                           \
    for (int i_ = 0; i_ < 2; ++i_) {                                            \
      const int g_ = wid + i_ * 4;                                              \
      const int r_ = g_ * 16 + sr;                                              \
      const int cd_ = cs ^ ((r_ >> 1) & 3);                                     \
      load16_to_lds(Ab + (size_t)(rowBase + r_) * BD + (k0) + cd_ * 8,          \
                    &Alds[bi][g_ * 512]);                                       \
      load16_to_lds(Ab + (size_t)(colBase + r_) * BD + (k0) + cd_ * 8,          \
                    &Blds[bi][g_ * 512]);                                       \
    } }

  GRSTAGE(0, 0);
  int cur = 0;
  for (int k0 = 0; k0 < DIMN; k0 += 32, cur ^= 1) {
    if (k0 + 32 < DIMN) {
      GRSTAGE(cur ^ 1, k0 + 32);
      asm volatile("s_waitcnt vmcnt(4)" ::: "memory");
    } else {
      asm volatile("s_waitcnt vmcnt(0)" ::: "memory");
    }
    __builtin_amdgcn_s_barrier();
    asm volatile("" ::: "memory");
    f16x8 af[4], bf[4];
    #pragma unroll
    for (int mi = 0; mi < 4; ++mi) {
      const int r = wm * 64 + mi * 16 + l15;
      af[mi] = *(const f16x8*)(&Alds[cur][r * 32 + (quad ^ swz) * 8]);
    }
    #pragma unroll
    for (int ni = 0; ni < 4; ++ni) {
      const int r = wn * 64 + ni * 16 + l15;
      bf[ni] = *(const f16x8*)(&Blds[cur][r * 32 + (quad ^ swz) * 8]);
    }
    #pragma unroll
    for (int mi = 0; mi < 4; ++mi)
      #pragma unroll
      for (int ni = 0; ni < 4; ++ni)
        acc[mi][ni] = __builtin_amdgcn_mfma_f32_16x16x32_f16(af[mi], bf[ni], acc[mi][ni], 0, 0, 0);
    asm volatile("" ::: "memory");
    __builtin_amdgcn_s_barrier();
  }
#undef GRSTAGE

  f16* Gb = Gout + (size_t)bz * (T_STEPS * T_STEPS);
  #pragma unroll
  for (int mi = 0; mi < 4; ++mi) {
    const int m0 = rowBase + wm * 64 + mi * 16 + quad * 4;
    #pragma unroll
    for (int j = 0; j < 4; ++j) {
      #pragma unroll
      for (int ni = 0; ni < 4; ++ni) {
        const int n = colBase + wn * 64 + ni * 16 + l15;
        Gb[(size_t)(m0 + j) * T_STEPS + n] = (f16)acc[mi][ni][j];
      }
    }
  }
}

// ---------- P[b][s] = h0[b] . w_s ----------
__global__ __launch_bounds__(256) void gemv_p(
    const f16* __restrict__ Wm, const float* __restrict__ h0,
    float* __restrict__ P) {
  const int b = blockIdx.x, sg = blockIdx.y;
  const int w = threadIdx.x >> 6, l = threadIdx.x & 63;
  float h[16];
  {
    const float* hp = h0 + (size_t)b * DIMN + l * 16;
    #pragma unroll
    for (int i = 0; i < 4; ++i) {
      float4 a = *(const float4*)(hp + i * 4);
      h[i*4+0] = a.x; h[i*4+1] = a.y; h[i*4+2] = a.z; h[i*4+3] = a.w;
    }
  }
  for (int k = 0; k < 16; ++k) {
    const int s = sg * 64 + w * 16 + k;
    const f16* wp = Wm + (size_t)s * BD + (size_t)b * DIMN + l * 16;
    f16x8 a0 = *(const f16x8*)(wp);
    f16x8 a1 = *(const f16x8*)(wp + 8);
    float acc = 0.f;
    #pragma unroll
    for (int i = 0; i < 8; ++i) acc = fmaf((float)a0[i], h[i], acc);
    #pragma unroll
    for (int i = 0; i < 8; ++i) acc = fmaf((float)a1[i], h[i+8], acc);
    acc = wave_allsum(acc);
    if (l == 0) P[(size_t)b * 512 + s] = acc;
  }
}

// ---------- scalar scan: the sequential chain, D-free (verified round 6) ----------
template<int SHIFT>
__global__ __launch_bounds__(64, 1) void scalar_scan(
    const f16* __restrict__ Gm, const float* __restrict__ P,
    const float* __restrict__ h0,
    float* __restrict__ Carr, float* __restrict__ Sarr) {
  const int b = blockIdx.x, l = threadIdx.x;
  const f16* Gb = Gm + (size_t)b * (T_STEPS * T_STEPS);
  float N;
  {
    const float* hp = h0 + (size_t)b * DIMN + l * 16;
    float na = 0.f;
    #pragma unroll
    for (int i = 0; i < 4; ++i) {
      float4 a = *(const float4*)(hp + i * 4);
      na = fmaf(a.x, a.x, na); na = fmaf(a.y, a.y, na);
      na = fmaf(a.z, a.z, na); na = fmaf(a.w, a.w, na);
    }
    N = wave_allsum(na);
  }
  float d[8];
  {
    float4 p0 = *(const float4*)(P + (size_t)b * 512 + l * 8);
    float4 p1 = *(const float4*)(P + (size_t)b * 512 + l * 8 + 4);
    d[0]=p0.x; d[1]=p0.y; d[2]=p0.z; d[3]=p0.w;
    d[4]=p1.x; d[5]=p1.y; d[6]=p1.z; d[7]=p1.w;
  }
  float gd[8];
  #pragma unroll
  for (int j = 0; j < 8; ++j)
    gd[j] = (float)Gb[(size_t)(l * 8 + j) * T_STEPS + (l * 8 + j)];
  f16x8 grow[8];
  #pragma unroll
  for (int j = 0; j < 8; ++j)
    grow[j] = *(const f16x8*)(Gb + (size_t)j * T_STEPS + l * 8);

  float c = 1.f, ic = 1.f, kk = 1.f / DIMN;
  if (SHIFT && l == 0) Sarr[(size_t)b * 512] = 1.f;
  float ccap = 1.f, iccap = 1.f;

  for (int tb = 0; tb < T_STEPS; tb += 8) {
    const int a = tb >> 3;
    #pragma unroll
    for (int J = 0; J < 8; ++J) {
      const int t = tb + J;
      f16x8 g = grow[J];
      int tn = t + 8; if (tn > T_STEPS - 1) tn = T_STEPS - 1;
      grow[J] = *(const f16x8*)(Gb + (size_t)tn * T_STEPS + l * 8);
      const float e   = __int_as_float(__builtin_amdgcn_readlane(__float_as_int(d[J]),  a));
      const float gtt = __int_as_float(__builtin_amdgcn_readlane(__float_as_int(gd[J]), a));
      const float cold = c;
      #pragma unroll
      for (int j2 = 0; j2 < 8; ++j2) d[j2] = fmaf(cold, (float)g[j2], d[j2]);
      N = fmaf(2.f * cold, e, fmaf(cold * cold, gtt, N));
      const float m   = fmaf(N, kk, 1e-6f);
      const float rho = __builtin_amdgcn_rsqf(m);
      c  = cold * (m * rho);
      ic = ic * rho;
      kk = kk * (rho * rho);
      ccap  = (l == J) ? cold : ccap;
      iccap = (l == J) ? ic   : iccap;
    }
    if (l < 8) {
      Carr[(size_t)b * 512 + tb + l] = ccap;
      const int sidx = tb + SHIFT + l;
      if (sidx < T_STEPS) Sarr[(size_t)b * 512 + sidx] = iccap;
    }
  }
}

// ---------- phase A: PS[tc][b][d] = sum_{t in chunk tc} c_t * w_t[b][d] ----------
__global__ __launch_bounds__(64) void chunk_partial(
    const f16* __restrict__ Win, const float* __restrict__ Carr,
    float* __restrict__ PS) {
  const int b = blockIdx.x, dcy = blockIdx.y, tc = blockIdx.z;
  const int l = threadIdx.x;
  const size_t base = (size_t)b * DIMN + dcy * 256 + l * 4;
  const float* Cb = Carr + (size_t)b * 512;
  const int t0 = tc * 64;
  float a0 = 0.f, a1 = 0.f, a2 = 0.f, a3 = 0.f;
  f16x4 ring[8];
  #pragma unroll
  for (int j = 0; j < 8; ++j)
    ring[j] = *(const f16x4*)(Win + (size_t)(t0 + j) * BD + base);
  for (int tt = 0; tt < 64; tt += 8) {
    float4 ca = *(const float4*)(Cb + t0 + tt);
    float4 cz = *(const float4*)(Cb + t0 + tt + 4);
    const float cc[8] = {ca.x, ca.y, ca.z, ca.w, cz.x, cz.y, cz.z, cz.w};
    #pragma unroll
    for (int J = 0; J < 8; ++J) {
      f16x4 w = ring[J];
      int tn = t0 + tt + J + 8; if (tn > T_STEPS - 1) tn = T_STEPS - 1;
      ring[J] = *(const f16x4*)(Win + (size_t)tn * BD + base);
      a0 = fmaf(cc[J], (float)w[0], a0);
      a1 = fmaf(cc[J], (float)w[1], a1);
      a2 = fmaf(cc[J], (float)w[2], a2);
      a3 = fmaf(cc[J], (float)w[3], a3);
    }
  }
  *(float4*)(PS + (size_t)tc * BD + base) = make_float4(a0, a1, a2, a3);
}

// ---------- phase B pass 0: G0[t+1] = u_{t+1}; G0[0] = h0 ----------
__global__ __launch_bounds__(64) void recomb0B(
    const f16* __restrict__ Wx, const float* __restrict__ h0,
    const float* __restrict__ Carr, const float* __restrict__ PS,
    f16* __restrict__ G0) {
  const int b = blockIdx.x, dcy = blockIdx.y, tc = blockIdx.z;
  const int l = threadIdx.x;
  const size_t base = (size_t)b * DIMN + dcy * 256 + l * 4;
  float4 h = *(const float4*)(h0 + base);
  float u0 = h.x, u1 = h.y, u2 = h.z, u3 = h.w;
  for (int p = 0; p < tc; ++p) {
    float4 ps = *(const float4*)(PS + (size_t)p * BD + base);
    u0 += ps.x; u1 += ps.y; u2 += ps.z; u3 += ps.w;
  }
  if (tc == 0) {
    U4 g; g.p[0] = pkrtz(u0, u1); g.p[1] = pkrtz(u2, u3);
    *(f16x4*)(G0 + base) = g.v;
  }
  const float* Cb = Carr + (size_t)b * 512;
  const int t0 = tc * 64;
  f16x4 ring[8];
  #pragma unroll
  for (int j = 0; j < 8; ++j)
    ring[j] = *(const f16x4*)(Wx + (size_t)(t0 + j) * BD + base);
  for (int tt = 0; tt < 64; tt += 8) {
    float4 ca = *(const float4*)(Cb + t0 + tt);
    float4 cz = *(const float4*)(Cb + t0 + tt + 4);
    const float cc[8] = {ca.x, ca.y, ca.z, ca.w, cz.x, cz.y, cz.z, cz.w};
    #pragma unroll
    for (int J = 0; J < 8; ++J) {
      const int t = t0 + tt + J;
      f16x4 w = ring[J];
      int tn = t + 8; if (tn > T_STEPS - 1) tn = T_STEPS - 1;
      ring[J] = *(const f16x4*)(Wx + (size_t)tn * BD + base);
      u0 = fmaf(cc[J], (float)w[0], u0);
      u1 = fmaf(cc[J], (float)w[1], u1);
      u2 = fmaf(cc[J], (float)w[2], u2);
      u3 = fmaf(cc[J], (float)w[3], u3);
      if (t < T_STEPS - 1) {
        U4 g; g.p[0] = pkrtz(u0, u1); g.p[1] = pkrtz(u2, u3);
        *(f16x4*)(G0 + (size_t)(t + 1) * BD + base) = g.v;
      }
    }
  }
}

// ---------- phase B pass 1 + expand ----------
__global__ __launch_bounds__(64) void recomb1B(
    const f16* __restrict__ Cin, const float* __restrict__ h0,
    const float* __restrict__ Carr, const float* __restrict__ Sarr,
    const float* __restrict__ PS,
    float* __restrict__ outs, float* __restrict__ hout) {
  const int b = blockIdx.x, dcy = blockIdx.y, tc = blockIdx.z;
  const int l = threadIdx.x;
  const size_t base = (size_t)b * DIMN + dcy * 256 + l * 4;
  if (tc == 8) {                        // tail: hout[0] = h0
    float4 a = *(const float4*)(h0 + base);
    *(float4*)(hout + base) = a;
    return;
  }
  float4 h = *(const float4*)(h0 + base);
  float u0 = h.x, u1 = h.y, u2 = h.z, u3 = h.w;
  for (int p = 0; p < tc; ++p) {
    float4 ps = *(const float4*)(PS + (size_t)p * BD + base);
    u0 += ps.x; u1 += ps.y; u2 += ps.z; u3 += ps.w;
  }
  const float* Cb = Carr + (size_t)b * 512;
  const float* Sb = Sarr + (size_t)b * 512;
  const int t0 = tc * 64;
  f16x4 ring[8];
  #pragma unroll
  for (int j = 0; j < 8; ++j)
    ring[j] = *(const f16x4*)(Cin + (size_t)(t0 + j) * BD + base);
  for (int tt = 0; tt < 64; tt += 8) {
    float4 ca = *(const float4*)(Cb + t0 + tt);
    float4 cz = *(const float4*)(Cb + t0 + tt + 4);
    float4 sa = *(const float4*)(Sb + t0 + tt);
    float4 sz = *(const float4*)(Sb + t0 + tt + 4);
    const float cc[8] = {ca.x, ca.y, ca.z, ca.w, cz.x, cz.y, cz.z, cz.w};
    const float ss[8] = {sa.x, sa.y, sa.z, sa.w, sz.x, sz.y, sz.z, sz.w};
    #pragma unroll
    for (int J = 0; J < 8; ++J) {
      const int t = t0 + tt + J;
      f16x4 w = ring[J];
      int tn = t + 8; if (tn > T_STEPS - 1) tn = T_STEPS - 1;
      ring[J] = *(const f16x4*)(Cin + (size_t)tn * BD + base);
      u0 = fmaf(cc[J], (float)w[0], u0);
      u1 = fmaf(cc[J], (float)w[1], u1);
      u2 = fmaf(cc[J], (float)w[2], u2);
      u3 = fmaf(cc[J], (float)w[3], u3);
      const float v0 = ss[J] * u0, v1 = ss[J] * u1;
      const float v2 = ss[J] * u2, v3 = ss[J] * u3;
      const float o0 = v0 * v0 / (1.f + expf(-v0));
      const float o1 = v1 * v1 / (1.f + expf(-v1));
      const float o2 = v2 * v2 / (1.f + expf(-v2));
      const float o3 = v3 * v3 / (1.f + expf(-v3));
      *(float4*)(outs + (size_t)t * BD + base) = make_float4(o0, o1, o2, o3);
      *(float4*)(hout + (size_t)(t + 1) * BD + base) = make_float4(v0, v1, v2, v3);
    }
  }
}

extern "C" void kernel_launch(void* const* d_in, const int* in_sizes, int n_in,
                              void* d_out, int out_size, void* d_ws, size_t ws_size,
                              hipStream_t stream) {
  const float* x    = (const float*)d_in[0];
  const float* h0   = (const float*)d_in[1];
  const float* W    = (const float*)d_in[2];
  const float* Wh   = (const float*)d_in[3];
  const float* bias = (const float*)d_in[4];
  const float* la   = (const float*)d_in[5];
  const float* lb   = (const float*)d_in[6];

  char* ws = (char*)d_ws;
  f16* XH   = (f16*)(ws);                       // 32MB; dead after GEMM0
  f16* GRAM = (f16*)(ws);                       // 16.78MB, reuses XH slot
  f16* W16  = (f16*)(ws + 33554432ull);         // 2MB; dead after GEMM0
  f16* WH16 = (f16*)(ws + 35651584ull);         // 2MB; dead after GEMM1
  f16* WX16 = (f16*)(ws + 37748736ull);         // 32MB
  f16* G0   = (f16*)(ws + 71303168ull);         // 32MB
  f16* C16  = (f16*)(ws + 104857600ull);        // 32MB
  // scalar arrays + chunk partials in dead weight slots
  float* S0  = (float*)(ws + 33554432ull);
  float* C0  = (float*)(ws + 33554432ull + 65536ull);
  float* P0  = (float*)(ws + 33554432ull + 131072ull);
  float* PS0 = (float*)(ws + 33554432ull + 196608ull);   // 1MB, W16 slot
  float* S1  = (float*)(ws + 35651584ull);
  float* C1  = (float*)(ws + 35651584ull + 65536ull);
  float* P1  = (float*)(ws + 35651584ull + 131072ull);
  float* PS1 = (float*)(ws + 35651584ull + 196608ull);   // 1MB, WH16 slot

  float* outs = (float*)d_out;
  float* hout = outs + (size_t)T_STEPS * BD;

  cvt_f32_f16<<<dim3((MROWS * DIMN / 8) / 256), 256, 0, stream>>>(x, XH, MROWS * DIMN / 8);
  cvt_f32_f16<<<dim3((DIMN * DIMN / 8) / 256), 256, 0, stream>>>(W, W16, DIMN * DIMN / 8);
  cvt_f32_f16<<<dim3((DIMN * DIMN / 8) / 256), 256, 0, stream>>>(Wh, WH16, DIMN * DIMN / 8);

  // WX16 = alpha * (x @ W^T + b)
  gemm_bt_f16<<<dim3(MROWS / 128, DIMN / 128), 256, 0, stream>>>(
      XH, W16, bias, WX16, la, lb, nullptr, nullptr, 0);

  // pass 0: Gram, P0, scalar chain, chunked recombine
  gram_f16<<<dim3(4, 4, BATCH), 256, 0, stream>>>(WX16, GRAM);
  gemv_p<<<dim3(BATCH, 8), 256, 0, stream>>>(WX16, h0, P0);
  scalar_scan<1><<<dim3(BATCH), 64, 0, stream>>>(GRAM, P0, h0, C0, S0);
  chunk_partial<<<dim3(BATCH, 4, 8), 64, 0, stream>>>(WX16, C0, PS0);
  recomb0B<<<dim3(BATCH, 4, 8), 64, 0, stream>>>(WX16, h0, C0, PS0, G0);

  // C16 = WX16 + beta * ic0[row] * (G0 @ Wh^T)
  gemm_bt_f16<<<dim3(MROWS / 128, DIMN / 128), 256, 0, stream>>>(
      G0, WH16, nullptr, C16, la, lb, S0, WX16, 1);

  // pass 1: Gram, P1, scalar chain, chunked recombine + expand (fused)
  gram_f16<<<dim3(4, 4, BATCH), 256, 0, stream>>>(C16, GRAM);
  gemv_p<<<dim3(BATCH, 8), 256, 0, stream>>>(C16, h0, P1);
  scalar_scan<0><<<dim3(BATCH), 64, 0, stream>>>(GRAM, P1, h0, C1, S1);
  chunk_partial<<<dim3(BATCH, 4, 8), 64, 0, stream>>>(C16, C1, PS1);
  recomb1B<<<dim3(BATCH, 4, 9), 64, 0, stream>>>(C16, h0, C1, S1, PS1, outs, hout);
}